// Round 8
// baseline (1408.317 us; speedup 1.0000x reference)
//
#include <hip/hip_runtime.h>

#define N_NODES 50000
#define N_PAD   50048          // 782 * 64
#define N_EDGES 800000
#define N_REL   8
#define NSEG    (N_REL * N_NODES)      // 400000
#define SCAN_NB 391                    // ceil(NSEG / 1024)

typedef short bf16x8 __attribute__((ext_vector_type(8)));
typedef float f32x4  __attribute__((ext_vector_type(4)));

__device__ __forceinline__ ushort f2bf(float f) {
    union { float f; unsigned u; } c; c.f = f;
    unsigned u = c.u + 0x7fffu + ((c.u >> 16) & 1u);   // RNE
    return (ushort)(u >> 16);
}
__device__ __forceinline__ void add8(float* s, uint4 v) {
    unsigned u[4] = {v.x, v.y, v.z, v.w};
    #pragma unroll
    for (int k = 0; k < 4; ++k) {
        s[2 * k]     += __uint_as_float(u[k] << 16);
        s[2 * k + 1] += __uint_as_float(u[k] & 0xffff0000u);
    }
}
__device__ __forceinline__ void async16(const ushort* g, ushort* l) {
    __builtin_amdgcn_global_load_lds((const __attribute__((address_space(1))) void*)g,
                                     (__attribute__((address_space(3))) void*)l, 16, 0, 0);
}

// ---------------- edge preprocessing: counting sort by (rel*N + dst) ----------------

__global__ void count_edges(const int* __restrict__ dst, const int* __restrict__ et,
                            int* __restrict__ cnt) {
    int e = blockIdx.x * 256 + threadIdx.x;
    if (e < N_EDGES) atomicAdd(&cnt[et[e] * N_NODES + dst[e]], 1);
}

__global__ __launch_bounds__(256) void scan_pass1(const int* __restrict__ cnt,
                                                  int* __restrict__ sums) {
    __shared__ int sc[256];
    int b = blockIdx.x, t = threadIdx.x;
    int base = b * 1024 + t * 4;
    int v = 0;
    #pragma unroll
    for (int i = 0; i < 4; ++i) { int idx = base + i; if (idx < NSEG) v += cnt[idx]; }
    sc[t] = v; __syncthreads();
    for (int off = 1; off < 256; off <<= 1) {
        int x = (t >= off) ? sc[t - off] : 0;
        __syncthreads(); sc[t] += x; __syncthreads();
    }
    if (t == 255) sums[b] = sc[255];
}

__global__ __launch_bounds__(512) void scan_pass2(int* __restrict__ sums, int nb) {
    __shared__ int sc[512];
    int t = threadIdx.x;
    int v = (t < nb) ? sums[t] : 0;
    sc[t] = v; __syncthreads();
    for (int off = 1; off < 512; off <<= 1) {
        int x = (t >= off) ? sc[t - off] : 0;
        __syncthreads(); sc[t] += x; __syncthreads();
    }
    if (t < nb) sums[t] = sc[t] - v;     // exclusive
}

__global__ __launch_bounds__(256) void scan_pass3(const int* __restrict__ cnt,
                                                  const int* __restrict__ sums,
                                                  int* __restrict__ row_ptr) {
    __shared__ int sc[256];
    int b = blockIdx.x, t = threadIdx.x;
    int base = b * 1024 + t * 4;
    int e[4]; int v = 0;
    #pragma unroll
    for (int i = 0; i < 4; ++i) { int idx = base + i; e[i] = (idx < NSEG) ? cnt[idx] : 0; v += e[i]; }
    sc[t] = v; __syncthreads();
    for (int off = 1; off < 256; off <<= 1) {
        int x = (t >= off) ? sc[t - off] : 0;
        __syncthreads(); sc[t] += x; __syncthreads();
    }
    int run = sums[b] + (sc[t] - v);
    #pragma unroll
    for (int i = 0; i < 4; ++i) {
        int idx = base + i;
        if (idx < NSEG) row_ptr[idx] = run;
        run += e[i];
    }
    if (b == 0 && t == 0) row_ptr[NSEG] = N_EDGES;
}

// cnt doubles as the placement cursor (atomicSub); cnt is dead afterwards.
__global__ void place_edges(const int* __restrict__ src, const int* __restrict__ dst,
                            const int* __restrict__ et, const int* __restrict__ row_ptr,
                            int* __restrict__ cnt, int* __restrict__ sorted_src) {
    int e = blockIdx.x * 256 + threadIdx.x;
    if (e >= N_EDGES) return;
    int key = et[e] * N_NODES + dst[e];
    int old = atomicSub(&cnt[key], 1);
    sorted_src[row_ptr[key] + old - 1] = src[e];
}

// ---------------- weight packs ----------------

// aggregate-first layout: BT[col][kk], kk = r*K+i (r=8 -> root), col < 256
__global__ void convert_cat(const float* __restrict__ W, const float* __restrict__ root,
                            ushort* __restrict__ BT, int K) {
    int KT = 9 * K;
    int idx = blockIdx.x * 256 + threadIdx.x;
    if (idx >= 256 * KT) return;
    int col = idx / KT, kk = idx % KT;
    int r = kk / K, i = kk % K;
    float v = (r < N_REL) ? W[((size_t)r * K + i) * 256 + col] : root[(size_t)i * 256 + col];
    BT[idx] = f2bf(v);
}

// transform-first layout (layer 4): BT[col][k], col = r*64+o (r=8 -> root), pad to 640
__global__ void convert_t4(const float* __restrict__ W, const float* __restrict__ root,
                           ushort* __restrict__ BT) {
    const int K = 256, O = 64, NPAD = 640;
    int idx = blockIdx.x * 256 + threadIdx.x;
    if (idx >= NPAD * K) return;
    int col = idx / K, i = idx % K;
    float v = 0.0f;
    if (col < N_REL * O) {
        int r = col / O, o = col % O;
        v = W[((size_t)r * K + i) * O + o];
    } else if (col < (N_REL + 1) * O) {
        v = root[(size_t)i * O + (col - N_REL * O)];
    }
    BT[idx] = f2bf(v);
}

__global__ void f32_to_bf16(const float* __restrict__ in, ushort* __restrict__ out, int n4) {
    int i = blockIdx.x * 256 + threadIdx.x;
    if (i >= n4) return;
    float4 v = ((const float4*)in)[i];
    ushort4 s; s.x = f2bf(v.x); s.y = f2bf(v.y); s.z = f2bf(v.z); s.w = f2bf(v.w);
    ((ushort4*)out)[i] = s;
}

// ---------------- segment mean into wide-A layout: Agg[d][r*K + c] ----------------
// Thread owns (dst, rel, 8-col chunk); rel==8 = identity copy (root operand).
// Random reads hit h (~25 MB, L2/L3-resident); writes are sequential full lines.
template<int K>
__global__ __launch_bounds__(256)
void segsum_kernel(const ushort* __restrict__ h, const int* __restrict__ row_ptr,
                   const int* __restrict__ sorted_src, ushort* __restrict__ Agg) {
    constexpr int TPN = K / 8;
    constexpr int DPB = 256 / TPN;
    constexpr int KT = 9 * K;
    int d = blockIdx.x * DPB + (int)threadIdx.x / TPN;
    int r = blockIdx.y;                      // 0..8
    int c0 = ((int)threadIdx.x % TPN) * 8;
    if (d >= N_PAD) return;
    ushort* outp = Agg + (size_t)d * KT + r * K + c0;
    if (d >= N_NODES) { *(uint4*)outp = make_uint4(0u, 0u, 0u, 0u); return; }
    if (r == N_REL) {
        *(uint4*)outp = *(const uint4*)(h + (size_t)d * K + c0);
        return;
    }
    int base = r * N_NODES + d;
    int s0 = row_ptr[base], s1 = row_ptr[base + 1];
    float sum[8] = {};
    for (int e = s0; e < s1; ++e)
        add8(sum, *(const uint4*)(h + (size_t)sorted_src[e] * K + c0));
    float inv = (s1 > s0) ? 1.0f / (float)(s1 - s0) : 0.0f;
    ushort o[8];
    #pragma unroll
    for (int k = 0; k < 8; ++k) o[k] = f2bf(sum[k] * inv);
    *(uint4*)outp = *(const uint4*)o;
}

// ---------------- aggregate-first GEMM: h_out = relu(Agg[N_PAD,KT] @ BT[256,KT]^T + bias) ----------------
// 64 rows x 256 cols per block; register-prefetch pipeline (global->VGPR for step k+1
// issued before MFMA of step k) to hide per-step load latency — attacks round-4's
// vmcnt(0)-drain serialization on long-K streams. Epilogue: LDS transpose, full-line stores.
template<int KT>
__global__ __launch_bounds__(256)
void gemm_ag(const ushort* __restrict__ A, const ushort* __restrict__ BT,
             const float* __restrict__ bias, ushort* __restrict__ Out) {
    __shared__ ushort SMEM[10240];      // 20 KB: As 2048 | Bs 8192 ; epilogue Ts 4*2304
    ushort* As = SMEM;                  // 64 rows x 32 k
    ushort* Bs = SMEM + 2048;           // 256 cols x 32 k
    const int t = threadIdx.x;
    const int lane = t & 63, w = t >> 6;
    const int l16 = lane & 15, q = lane >> 4;
    const int wn = w * 64;
    const int row0 = blockIdx.x * 64;

    // chunk c=t: row=c>>2, koff=(c&3)*8; LDS offset = c*8 (ushorts)
    const ushort* Aptr = A + (size_t)(row0 + (t >> 2)) * KT + ((t & 3) << 3);
    const ushort* Bptr = BT + (size_t)(t >> 2) * KT + ((t & 3) << 3);

    uint4 rA = *(const uint4*)Aptr;
    uint4 rB[4];
    #pragma unroll
    for (int p = 0; p < 4; ++p) rB[p] = *(const uint4*)(Bptr + (size_t)p * 64 * KT);

    f32x4 acc[4][4] = {};

    for (int k0 = 0; k0 < KT; k0 += 32) {
        __syncthreads();                   // previous step's LDS reads done
        *(uint4*)&As[t * 8] = rA;
        #pragma unroll
        for (int p = 0; p < 4; ++p) *(uint4*)&Bs[(p * 256 + t) * 8] = rB[p];
        if (k0 + 32 < KT) {                // prefetch next step (latency hides under MFMA)
            rA = *(const uint4*)(Aptr + k0 + 32);
            #pragma unroll
            for (int p = 0; p < 4; ++p)
                rB[p] = *(const uint4*)(Bptr + (size_t)p * 64 * KT + k0 + 32);
        }
        __syncthreads();                   // LDS writes visible
        bf16x8 a[4], b[4];
        #pragma unroll
        for (int i = 0; i < 4; ++i) {
            a[i] = *(const bf16x8*)&As[(i * 16 + l16) * 32 + q * 8];
            b[i] = *(const bf16x8*)&Bs[(wn + i * 16 + l16) * 32 + q * 8];
        }
        #pragma unroll
        for (int i = 0; i < 4; ++i)
            #pragma unroll
            for (int j = 0; j < 4; ++j)
                acc[i][j] = __builtin_amdgcn_mfma_f32_16x16x32_bf16(a[i], b[j], acc[i][j], 0, 0, 0);
    }

    // epilogue: bias+relu, two-pass 32-row transpose via wave-private LDS, full-line stores
    __syncthreads();
    ushort* Ts = &SMEM[w * 2304];          // 32 rows x stride 72
    const int rr = lane >> 3;
    const int cc = (lane & 7) * 8;
    #pragma unroll
    for (int half = 0; half < 2; ++half) {
        #pragma unroll
        for (int i = 0; i < 2; ++i)
            #pragma unroll
            for (int j = 0; j < 4; ++j) {
                float bv = bias[wn + j * 16 + l16];
                #pragma unroll
                for (int r = 0; r < 4; ++r) {
                    float v = fmaxf(acc[half * 2 + i][j][r] + bv, 0.0f);
                    Ts[(i * 16 + q * 4 + r) * 72 + j * 16 + l16] = f2bf(v);
                }
            }
        #pragma unroll
        for (int p = 0; p < 4; ++p) {
            int row = p * 8 + rr;          // 0..31 local
            uint4 v = *(const uint4*)&Ts[row * 72 + cc];
            *(uint4*)(Out + (size_t)(row0 + half * 32 + row) * 256 + wn + cc) = v;
        }
    }
}

// ---------------- transform-first GEMM (layer 4 only; round-7 kernel) ----------------
template<int K>
__global__ __launch_bounds__(256)
void gemm_mfma(const ushort* __restrict__ A, const ushort* __restrict__ BT,
               ushort* __restrict__ Y, int NW) {
    __shared__ ushort SMEM[9216];
    ushort* As = SMEM;
    ushort* Bs = SMEM + 4096;
    const int t = threadIdx.x;
    const int lane = t & 63;
    const int w = t >> 6;
    const int l16 = lane & 15, q = lane >> 4;
    const int wm = (w & 1) * 64, wn = (w >> 1) * 64;
    const int col0 = blockIdx.x * 128;
    const int row0 = blockIdx.y * 128;

    const int c0i = w * 64 + lane;
    const int c1i = c0i + 256;
    const size_t ga0 = (size_t)(c0i >> 2) * K + (size_t)(c0i & 3) * 8;
    const size_t ga1 = (size_t)(c1i >> 2) * K + (size_t)(c1i & 3) * 8;
    const ushort* Ab = A + (size_t)row0 * K;
    const ushort* Bb = BT + (size_t)col0 * K;
    ushort* lA0 = &As[w * 512];
    ushort* lA1 = &As[(w + 4) * 512];
    ushort* lB0 = &Bs[w * 512];
    ushort* lB1 = &Bs[(w + 4) * 512];

    f32x4 acc[4][4] = {};

    #pragma unroll
    for (int k0 = 0; k0 < K; k0 += 32) {
        __syncthreads();
        async16(Ab + k0 + ga0, lA0);
        async16(Ab + k0 + ga1, lA1);
        async16(Bb + k0 + ga0, lB0);
        async16(Bb + k0 + ga1, lB1);
        __syncthreads();
        bf16x8 a[4], b[4];
        #pragma unroll
        for (int i = 0; i < 4; ++i) {
            a[i] = *(const bf16x8*)&As[(wm + i * 16 + l16) * 32 + q * 8];
            b[i] = *(const bf16x8*)&Bs[(wn + i * 16 + l16) * 32 + q * 8];
        }
        #pragma unroll
        for (int i = 0; i < 4; ++i)
            #pragma unroll
            for (int j = 0; j < 4; ++j)
                acc[i][j] = __builtin_amdgcn_mfma_f32_16x16x32_bf16(a[i], b[j], acc[i][j], 0, 0, 0);
    }

    __syncthreads();
    ushort* Ts = &SMEM[w * 32 * 72];
    const int rr = lane >> 3;
    const int cc = (lane & 7) * 8;
    #pragma unroll
    for (int half = 0; half < 2; ++half) {
        #pragma unroll
        for (int i = 0; i < 2; ++i)
            #pragma unroll
            for (int j = 0; j < 4; ++j)
                #pragma unroll
                for (int r = 0; r < 4; ++r)
                    Ts[(i * 16 + q * 4 + r) * 72 + j * 16 + l16] = f2bf(acc[half * 2 + i][j][r]);
        #pragma unroll
        for (int p = 0; p < 4; ++p) {
            int row = p * 8 + rr;
            uint4 v = *(const uint4*)&Ts[row * 72 + cc];
            *(uint4*)(Y + (size_t)(row0 + wm + half * 32 + row) * NW + col0 + wn + cc) = v;
        }
    }
}

// ---------------- layer-4 gather: out[d] = root + bias + sum_r mean_r (fp32 out) ----------------
__global__ __launch_bounds__(256)
void gather64(const ushort* __restrict__ Y, int NW,
              const int* __restrict__ row_ptr, const int* __restrict__ sorted_src,
              const float* __restrict__ bias, float* __restrict__ out) {
    constexpr int TPN = 8;                 // 64 cols / 8
    int d = blockIdx.x * 32 + threadIdx.x / TPN;
    if (d >= N_NODES) return;
    int c0 = (threadIdx.x % TPN) * 8;
    float sum[8] = {};
    add8(sum, *(const uint4*)(Y + (size_t)d * NW + N_REL * 64 + c0));   // root slice
    #pragma unroll
    for (int k = 0; k < 8; ++k) sum[k] += bias[c0 + k];
    for (int r = 0; r < N_REL; ++r) {
        int base = r * N_NODES + d;
        int s0 = row_ptr[base], s1 = row_ptr[base + 1];
        if (s1 <= s0) continue;
        float ps[8] = {};
        const ushort* Yc = Y + r * 64 + c0;
        for (int e = s0; e < s1; ++e)
            add8(ps, *(const uint4*)(Yc + (size_t)sorted_src[e] * NW));
        float inv = 1.0f / (float)(s1 - s0);
        #pragma unroll
        for (int k = 0; k < 8; ++k) sum[k] += ps[k] * inv;
    }
    float* p = out + (size_t)d * 64 + c0;
    *(float4*)p = make_float4(sum[0], sum[1], sum[2], sum[3]);
    *(float4*)(p + 4) = make_float4(sum[4], sum[5], sum[6], sum[7]);
}

// ---------------- host side ----------------

extern "C" void kernel_launch(void* const* d_in, const int* in_sizes, int n_in,
                              void* d_out, int out_size, void* d_ws, size_t ws_size,
                              hipStream_t stream) {
    const float* x  = (const float*)d_in[0];
    const int*   ei = (const int*)d_in[1];
    const int*   et = (const int*)d_in[2];
    const float* W[4]  = {(const float*)d_in[3], (const float*)d_in[6], (const float*)d_in[9],  (const float*)d_in[12]};
    const float* RT[4] = {(const float*)d_in[4], (const float*)d_in[7], (const float*)d_in[10], (const float*)d_in[13]};
    const float* BI[4] = {(const float*)d_in[5], (const float*)d_in[8], (const float*)d_in[11], (const float*)d_in[14]};
    const int* src = ei;
    const int* dst = ei + N_EDGES;

    // ---- workspace carve-up (~266 MB; same footprint as proven round-3 plan A) ----
    char* ws = (char*)d_ws;
    size_t off = 0;
    auto take = [&](size_t bytes) -> char* {
        char* p = ws + off;
        off = (off + bytes + 255) & ~(size_t)255;
        return p;
    };
    int* cnt        = (int*)take((size_t)NSEG * 4);
    int* row_ptr    = (int*)take((size_t)(NSEG + 1) * 4);
    int* sums       = (int*)take(512 * 4);
    int* sorted_src = (int*)take((size_t)N_EDGES * 4);
    ushort* BTc0 = (ushort*)take((size_t)256 * 1152 * 2);   // layer 1 (aggregate-first)
    ushort* BTc1 = (ushort*)take((size_t)256 * 2304 * 2);   // layer 2
    ushort* BTc2 = (ushort*)take((size_t)256 * 2304 * 2);   // layer 3
    ushort* BT4  = (ushort*)take((size_t)640 * 256 * 2);    // layer 4 (transform-first)
    ushort* hb   = (ushort*)take((size_t)N_PAD * 256 * 2);  // activations, bf16
    ushort* Agg  = (ushort*)take((size_t)N_PAD * 2304 * 2); // wide A operand / layer-4 Y

    // ---- edge preprocessing (once per call) ----
    hipMemsetAsync(cnt, 0, (size_t)NSEG * 4, stream);
    count_edges<<<(N_EDGES + 255) / 256, 256, 0, stream>>>(dst, et, cnt);
    scan_pass1<<<SCAN_NB, 256, 0, stream>>>(cnt, sums);
    scan_pass2<<<1, 512, 0, stream>>>(sums, SCAN_NB);
    scan_pass3<<<SCAN_NB, 256, 0, stream>>>(cnt, sums, row_ptr);
    place_edges<<<(N_EDGES + 255) / 256, 256, 0, stream>>>(src, dst, et, row_ptr, cnt, sorted_src);

    // ---- weight packs ----
    convert_cat<<<(256 * 1152 + 255) / 256, 256, 0, stream>>>(W[0], RT[0], BTc0, 128);
    convert_cat<<<(256 * 2304 + 255) / 256, 256, 0, stream>>>(W[1], RT[1], BTc1, 256);
    convert_cat<<<(256 * 2304 + 255) / 256, 256, 0, stream>>>(W[2], RT[2], BTc2, 256);
    convert_t4<<<(640 * 256 + 255) / 256, 256, 0, stream>>>(W[3], RT[3], BT4);

    // ---- input to bf16 ----
    f32_to_bf16<<<(N_NODES * 128 / 4 + 255) / 256, 256, 0, stream>>>(x, hb, N_NODES * 128 / 4);

    // ---- layers 1-3: aggregate-first (segsum + wide-K GEMM) ----
    segsum_kernel<128><<<dim3(N_PAD / 16, 9), 256, 0, stream>>>(hb, row_ptr, sorted_src, Agg);
    gemm_ag<1152><<<N_PAD / 64, 256, 0, stream>>>(Agg, BTc0, BI[0], hb);

    segsum_kernel<256><<<dim3(N_PAD / 8, 9), 256, 0, stream>>>(hb, row_ptr, sorted_src, Agg);
    gemm_ag<2304><<<N_PAD / 64, 256, 0, stream>>>(Agg, BTc1, BI[1], hb);

    segsum_kernel<256><<<dim3(N_PAD / 8, 9), 256, 0, stream>>>(hb, row_ptr, sorted_src, Agg);
    gemm_ag<2304><<<N_PAD / 64, 256, 0, stream>>>(Agg, BTc2, BI[2], hb);

    // ---- layer 4: transform-first (Y only 64 MB) ----
    dim3 g4(640 / 128, N_PAD / 128);
    gemm_mfma<256><<<g4, 256, 0, stream>>>(hb, BT4, Agg, 640);
    gather64<<<(N_NODES + 31) / 32, 256, 0, stream>>>(Agg, 640, row_ptr, sorted_src, BI[3], (float*)d_out);
}

// Round 9
// 969.965 us; speedup vs baseline: 1.4519x; 1.4519x over previous
//
#include <hip/hip_runtime.h>

#define N_NODES 50000
#define N_PAD   50048          // 782 * 64
#define N_EDGES 800000
#define N_REL   8
#define NSEG    (N_REL * N_NODES)      // 400000
#define SCAN_NB 391                    // ceil(NSEG / 1024)

typedef short bf16x8 __attribute__((ext_vector_type(8)));
typedef float f32x4  __attribute__((ext_vector_type(4)));

__device__ __forceinline__ ushort f2bf(float f) {
    union { float f; unsigned u; } c; c.f = f;
    unsigned u = c.u + 0x7fffu + ((c.u >> 16) & 1u);   // RNE
    return (ushort)(u >> 16);
}
__device__ __forceinline__ void add8(float* s, uint4 v) {
    unsigned u[4] = {v.x, v.y, v.z, v.w};
    #pragma unroll
    for (int k = 0; k < 4; ++k) {
        s[2 * k]     += __uint_as_float(u[k] << 16);
        s[2 * k + 1] += __uint_as_float(u[k] & 0xffff0000u);
    }
}
__device__ __forceinline__ void async16(const ushort* g, ushort* l) {
    __builtin_amdgcn_global_load_lds((const __attribute__((address_space(1))) void*)g,
                                     (__attribute__((address_space(3))) void*)l, 16, 0, 0);
}

// ---------------- edge preprocessing: counting sort by (rel*N + dst) ----------------

__global__ void count_edges(const int* __restrict__ dst, const int* __restrict__ et,
                            int* __restrict__ cnt) {
    int e = blockIdx.x * 256 + threadIdx.x;
    if (e < N_EDGES) atomicAdd(&cnt[et[e] * N_NODES + dst[e]], 1);
}

__global__ __launch_bounds__(256) void scan_pass1(const int* __restrict__ cnt,
                                                  int* __restrict__ sums) {
    __shared__ int sc[256];
    int b = blockIdx.x, t = threadIdx.x;
    int base = b * 1024 + t * 4;
    int v = 0;
    #pragma unroll
    for (int i = 0; i < 4; ++i) { int idx = base + i; if (idx < NSEG) v += cnt[idx]; }
    sc[t] = v; __syncthreads();
    for (int off = 1; off < 256; off <<= 1) {
        int x = (t >= off) ? sc[t - off] : 0;
        __syncthreads(); sc[t] += x; __syncthreads();
    }
    if (t == 255) sums[b] = sc[255];
}

__global__ __launch_bounds__(512) void scan_pass2(int* __restrict__ sums, int nb) {
    __shared__ int sc[512];
    int t = threadIdx.x;
    int v = (t < nb) ? sums[t] : 0;
    sc[t] = v; __syncthreads();
    for (int off = 1; off < 512; off <<= 1) {
        int x = (t >= off) ? sc[t - off] : 0;
        __syncthreads(); sc[t] += x; __syncthreads();
    }
    if (t < nb) sums[t] = sc[t] - v;     // exclusive
}

__global__ __launch_bounds__(256) void scan_pass3(const int* __restrict__ cnt,
                                                  const int* __restrict__ sums,
                                                  int* __restrict__ row_ptr) {
    __shared__ int sc[256];
    int b = blockIdx.x, t = threadIdx.x;
    int base = b * 1024 + t * 4;
    int e[4]; int v = 0;
    #pragma unroll
    for (int i = 0; i < 4; ++i) { int idx = base + i; e[i] = (idx < NSEG) ? cnt[idx] : 0; v += e[i]; }
    sc[t] = v; __syncthreads();
    for (int off = 1; off < 256; off <<= 1) {
        int x = (t >= off) ? sc[t - off] : 0;
        __syncthreads(); sc[t] += x; __syncthreads();
    }
    int run = sums[b] + (sc[t] - v);
    #pragma unroll
    for (int i = 0; i < 4; ++i) {
        int idx = base + i;
        if (idx < NSEG) row_ptr[idx] = run;
        run += e[i];
    }
    if (b == 0 && t == 0) row_ptr[NSEG] = N_EDGES;
}

// cnt doubles as the placement cursor (atomicSub); cnt is dead afterwards.
__global__ void place_edges(const int* __restrict__ src, const int* __restrict__ dst,
                            const int* __restrict__ et, const int* __restrict__ row_ptr,
                            int* __restrict__ cnt, int* __restrict__ sorted_src) {
    int e = blockIdx.x * 256 + threadIdx.x;
    if (e >= N_EDGES) return;
    int key = et[e] * N_NODES + dst[e];
    int old = atomicSub(&cnt[key], 1);
    sorted_src[row_ptr[key] + old - 1] = src[e];
}

// ---------------- weight pack: BT[col][k] bf16, col = r*O+o (r=8 -> root), zero-pad cols ----------------

__global__ void convert_weights(const float* __restrict__ W, const float* __restrict__ root,
                                ushort* __restrict__ BT, int K, int O, int NPAD) {
    int idx = blockIdx.x * 256 + threadIdx.x;
    if (idx >= NPAD * K) return;
    int col = idx / K, i = idx % K;
    float v = 0.0f;
    if (col < N_REL * O) {
        int r = col / O, o = col % O;
        v = W[((size_t)r * K + i) * O + o];
    } else if (col < (N_REL + 1) * O) {
        v = root[(size_t)i * O + (col - N_REL * O)];
    }
    BT[idx] = f2bf(v);
}

__global__ void f32_to_bf16(const float* __restrict__ in, ushort* __restrict__ out, int n4) {
    int i = blockIdx.x * 256 + threadIdx.x;
    if (i >= n4) return;
    float4 v = ((const float4*)in)[i];
    ushort4 s; s.x = f2bf(v.x); s.y = f2bf(v.y); s.z = f2bf(v.z); s.w = f2bf(v.w);
    ((ushort4*)out)[i] = s;
}

// ---------------- stripe-persistent GEMM: Y[64-row stripe] = A_stripe @ BT^T ----------------
// One block per 64-row stripe. A staged ONCE into LDS (padded stride -> conflict-free
// ds_read_b128); loop col-tiles x k-steps with double-buffered B via global_load_lds
// (B is 1.2 MB, L2-resident). A read from HBM exactly once (25.6 MB total).
// Epilogue per col-tile: wave-private LDS transpose (no barrier), full-line 128B stores.
template<int K, int CTS, int OUTW>
__global__ __launch_bounds__(256)
void gemm_stripe(const ushort* __restrict__ A, const ushort* __restrict__ BT,
                 ushort* __restrict__ Y) {
    constexpr int AP  = K + 8;          // padded A stride: 2-way bank pattern (free)
    constexpr int KST = K / 32;
    constexpr int NS  = CTS * KST;
    __shared__ ushort As[64 * AP];
    __shared__ ushort Bs[2][4096];      // 128 cols x 32 k per buffer
    __shared__ ushort Ts[4 * 1152];     // per-wave 16 x 72 transpose scratch
    const int t = threadIdx.x;
    const int lane = t & 63, w = t >> 6;
    const int l16 = lane & 15, q = lane >> 4;
    const int wm = (w & 1) * 32, wn = (w >> 1) * 64;   // wave tile: 32 rows x 64 cols
    const int row0 = blockIdx.x * 64;

    // ---- stage A stripe once (regular ds_write_b128; padding allowed) ----
    {
        constexpr int RC = K / 8;       // 16B chunks per row
        #pragma unroll
        for (int i = 0; i < 64 * RC / 256; ++i) {
            int c = i * 256 + t;
            int row = c / RC, ko = (c % RC) * 8;
            uint4 v = *(const uint4*)(A + (size_t)(row0 + row) * K + ko);
            *(uint4*)&As[row * AP + ko] = v;
        }
    }

    // B staging: chunk cB covers col=cB>>2, koff=(cB&3)*8; +64 cols for second half
    const int cB = w * 64 + lane;       // wave-uniform base + lane*16 (async16 reqt)
    const int bcol = cB >> 2, bko = (cB & 3) * 8;
    auto stageB = [&](int s, int buf) {
        const ushort* Bb = BT + (size_t)((s / KST) * 128) * K + (s % KST) * 32;
        async16(Bb + (size_t)bcol * K + bko, &Bs[buf][cB * 8]);
        async16(Bb + (size_t)(bcol + 64) * K + bko, &Bs[buf][cB * 8 + 2048]);
    };

    f32x4 acc[2][4] = {};
    stageB(0, 0);

    for (int s = 0; s < NS; ++s) {
        const int buf = s & 1;
        __syncthreads();                 // drains B[s] (vmcnt) + As writes / prior reads
        if (s + 1 < NS) stageB(s + 1, buf ^ 1);   // flies during MFMA of step s
        const int k0 = (s % KST) * 32;
        bf16x8 a[2], b[4];
        #pragma unroll
        for (int i = 0; i < 2; ++i)
            a[i] = *(const bf16x8*)&As[(wm + i * 16 + l16) * AP + k0 + q * 8];
        #pragma unroll
        for (int j = 0; j < 4; ++j)
            b[j] = *(const bf16x8*)&Bs[buf][(wn + j * 16 + l16) * 32 + q * 8];
        #pragma unroll
        for (int i = 0; i < 2; ++i)
            #pragma unroll
            for (int j = 0; j < 4; ++j)
                acc[i][j] = __builtin_amdgcn_mfma_f32_16x16x32_bf16(a[i], b[j], acc[i][j], 0, 0, 0);

        if ((s + 1) % KST == 0) {
            // ---- epilogue for finished col-tile ct (wave-private; lgkm-ordered) ----
            const int ct = s / KST;
            ushort* Tw = &Ts[w * 1152];
            const int rr = lane >> 3, cc = (lane & 7) * 8;
            #pragma unroll
            for (int i = 0; i < 2; ++i) {      // two 16-row halves of wave's 32 rows
                #pragma unroll
                for (int j = 0; j < 4; ++j)
                    #pragma unroll
                    for (int r = 0; r < 4; ++r)
                        Tw[(q * 4 + r) * 72 + j * 16 + l16] = f2bf(acc[i][j][r]);
                #pragma unroll
                for (int p = 0; p < 2; ++p) {
                    int row = p * 8 + rr;      // 0..15 local
                    uint4 v = *(const uint4*)&Tw[row * 72 + cc];
                    *(uint4*)(Y + (size_t)(row0 + wm + i * 16 + row) * OUTW
                              + ct * 128 + wn + cc) = v;
                }
                #pragma unroll
                for (int j = 0; j < 4; ++j) acc[i][j] = (f32x4){0.f, 0.f, 0.f, 0.f};
            }
        }
    }
}

// ---------------- fused gather: out[d] = act( root + bias + sum_r mean_r ) ----------------
// Thread owns (dst node, 8-col chunk); segment bounds preloaded for MLP; no atomics.
template<int O>
__global__ __launch_bounds__(256)
void gather_kernel(const ushort* __restrict__ Y, int NW,
                   const int* __restrict__ row_ptr, const int* __restrict__ sorted_src,
                   const float* __restrict__ bias,
                   float* __restrict__ out_f32, ushort* __restrict__ out_bf16, int relu) {
    constexpr int TPN = O / 8;
    int d = blockIdx.x * (256 / TPN) + threadIdx.x / TPN;
    if (d >= N_NODES) return;
    int c0 = (threadIdx.x % TPN) * 8;
    // preload all segment bounds (independent loads -> MLP)
    int s0[N_REL], s1[N_REL];
    #pragma unroll
    for (int r = 0; r < N_REL; ++r) {
        s0[r] = row_ptr[r * N_NODES + d];
        s1[r] = row_ptr[r * N_NODES + d + 1];
    }
    float sum[8] = {};
    add8(sum, *(const uint4*)(Y + (size_t)d * NW + N_REL * O + c0));   // root slice
    #pragma unroll
    for (int k = 0; k < 8; ++k) sum[k] += bias[c0 + k];
    for (int r = 0; r < N_REL; ++r) {
        if (s1[r] <= s0[r]) continue;
        float ps[8] = {};
        const ushort* Yc = Y + r * O + c0;
        for (int e = s0[r]; e < s1[r]; ++e)
            add8(ps, *(const uint4*)(Yc + (size_t)sorted_src[e] * NW));
        float inv = 1.0f / (float)(s1[r] - s0[r]);
        #pragma unroll
        for (int k = 0; k < 8; ++k) sum[k] += ps[k] * inv;
    }
    if (relu) {
        #pragma unroll
        for (int k = 0; k < 8; ++k) sum[k] = fmaxf(sum[k], 0.0f);
    }
    if (out_bf16) {
        ushort o[8];
        #pragma unroll
        for (int k = 0; k < 8; ++k) o[k] = f2bf(sum[k]);
        *(uint4*)(out_bf16 + (size_t)d * O + c0) = *(const uint4*)o;
    } else {
        float* p = out_f32 + (size_t)d * O + c0;
        *(float4*)p = make_float4(sum[0], sum[1], sum[2], sum[3]);
        *(float4*)(p + 4) = make_float4(sum[4], sum[5], sum[6], sum[7]);
    }
}

// ---------------- host side ----------------

extern "C" void kernel_launch(void* const* d_in, const int* in_sizes, int n_in,
                              void* d_out, int out_size, void* d_ws, size_t ws_size,
                              hipStream_t stream) {
    const float* x  = (const float*)d_in[0];
    const int*   ei = (const int*)d_in[1];
    const int*   et = (const int*)d_in[2];
    const float* W[4]  = {(const float*)d_in[3], (const float*)d_in[6], (const float*)d_in[9],  (const float*)d_in[12]};
    const float* RT[4] = {(const float*)d_in[4], (const float*)d_in[7], (const float*)d_in[10], (const float*)d_in[13]};
    const float* BI[4] = {(const float*)d_in[5], (const float*)d_in[8], (const float*)d_in[11], (const float*)d_in[14]};
    const int KS[4] = {128, 256, 256, 256};
    const int OS[4] = {256, 256, 256, 64};
    const int NP[4] = {2304, 2304, 2304, 640};   // packed+padded BT rows (= Y width)
    const int* src = ei;
    const int* dst = ei + N_EDGES;

    // ---- workspace carve-up (same footprint as proven round-3 plan A) ----
    char* ws = (char*)d_ws;
    size_t off = 0;
    auto take = [&](size_t bytes) -> char* {
        char* p = ws + off;
        off = (off + bytes + 255) & ~(size_t)255;
        return p;
    };
    int* cnt        = (int*)take((size_t)NSEG * 4);
    int* row_ptr    = (int*)take((size_t)(NSEG + 1) * 4);
    int* sums       = (int*)take(512 * 4);
    int* sorted_src = (int*)take((size_t)N_EDGES * 4);
    ushort* BTp[4];
    for (int l = 0; l < 4; ++l) BTp[l] = (ushort*)take((size_t)NP[l] * KS[l] * 2);
    ushort* hb = (ushort*)take((size_t)N_PAD * 256 * 2);
    ushort* Yb = (ushort*)take((size_t)N_PAD * 2304 * 2);

    // ---- edge preprocessing (once per call) ----
    hipMemsetAsync(cnt, 0, (size_t)NSEG * 4, stream);
    count_edges<<<(N_EDGES + 255) / 256, 256, 0, stream>>>(dst, et, cnt);
    scan_pass1<<<SCAN_NB, 256, 0, stream>>>(cnt, sums);
    scan_pass2<<<1, 512, 0, stream>>>(sums, SCAN_NB);
    scan_pass3<<<SCAN_NB, 256, 0, stream>>>(cnt, sums, row_ptr);
    place_edges<<<(N_EDGES + 255) / 256, 256, 0, stream>>>(src, dst, et, row_ptr, cnt, sorted_src);

    // ---- weight pack ----
    for (int l = 0; l < 4; ++l) {
        int n = NP[l] * KS[l];
        convert_weights<<<(n + 255) / 256, 256, 0, stream>>>(W[l], RT[l], BTp[l], KS[l], OS[l], NP[l]);
    }

    // ---- input to bf16 (+ zero the 48 pad rows of the 128-wide layer-1 input) ----
    f32_to_bf16<<<(N_NODES * 128 / 4 + 255) / 256, 256, 0, stream>>>(x, hb, N_NODES * 128 / 4);
    hipMemsetAsync(hb + (size_t)N_NODES * 128, 0, (size_t)(N_PAD - N_NODES) * 128 * 2, stream);

    // ---- 4 layers: stripe-persistent GEMM + fused gather ----
    gemm_stripe<128, 18, 2304><<<N_PAD / 64, 256, 0, stream>>>(hb, BTp[0], Yb);
    gather_kernel<256><<<dim3((N_NODES + 7) / 8), 256, 0, stream>>>(
        Yb, 2304, row_ptr, sorted_src, BI[0], nullptr, hb, 1);

    gemm_stripe<256, 18, 2304><<<N_PAD / 64, 256, 0, stream>>>(hb, BTp[1], Yb);
    gather_kernel<256><<<dim3((N_NODES + 7) / 8), 256, 0, stream>>>(
        Yb, 2304, row_ptr, sorted_src, BI[1], nullptr, hb, 1);

    gemm_stripe<256, 18, 2304><<<N_PAD / 64, 256, 0, stream>>>(hb, BTp[2], Yb);
    gather_kernel<256><<<dim3((N_NODES + 7) / 8), 256, 0, stream>>>(
        Yb, 2304, row_ptr, sorted_src, BI[2], nullptr, hb, 1);

    gemm_stripe<256, 5, 640><<<N_PAD / 64, 256, 0, stream>>>(hb, BTp[3], Yb);
    gather_kernel<64><<<dim3((N_NODES + 31) / 32), 256, 0, stream>>>(
        Yb, 640, row_ptr, sorted_src, BI[3], (float*)d_out, nullptr, 0);
}

// Round 10
// 723.362 us; speedup vs baseline: 1.9469x; 1.3409x over previous
//
#include <hip/hip_runtime.h>

#define N_NODES 50000
#define N_PAD   50048          // 391 * 128
#define N_EDGES 800000
#define N_REL   8
#define NSEG    (N_REL * N_NODES)      // 400000
#define SCAN_NB 391                    // ceil(NSEG / 1024)
#define NSTRIPE 391                    // 128-row stripes
#define SPX     49                     // ceil(391/8) stripes per XCD

typedef short bf16x8 __attribute__((ext_vector_type(8)));
typedef float f32x4  __attribute__((ext_vector_type(4)));

__device__ __forceinline__ ushort f2bf(float f) {
    union { float f; unsigned u; } c; c.f = f;
    unsigned u = c.u + 0x7fffu + ((c.u >> 16) & 1u);   // RNE
    return (ushort)(u >> 16);
}
__device__ __forceinline__ void add8(float* s, uint4 v) {
    unsigned u[4] = {v.x, v.y, v.z, v.w};
    #pragma unroll
    for (int k = 0; k < 4; ++k) {
        s[2 * k]     += __uint_as_float(u[k] << 16);
        s[2 * k + 1] += __uint_as_float(u[k] & 0xffff0000u);
    }
}
__device__ __forceinline__ void async16(const ushort* g, ushort* l) {
    __builtin_amdgcn_global_load_lds((const __attribute__((address_space(1))) void*)g,
                                     (__attribute__((address_space(3))) void*)l, 16, 0, 0);
}

// ---------------- edge preprocessing: counting sort by (rel*N + dst) ----------------

__global__ void count_edges(const int* __restrict__ dst, const int* __restrict__ et,
                            int* __restrict__ cnt) {
    int e = blockIdx.x * 256 + threadIdx.x;
    if (e < N_EDGES) atomicAdd(&cnt[et[e] * N_NODES + dst[e]], 1);
}

__global__ __launch_bounds__(256) void scan_pass1(const int* __restrict__ cnt,
                                                  int* __restrict__ sums) {
    __shared__ int sc[256];
    int b = blockIdx.x, t = threadIdx.x;
    int base = b * 1024 + t * 4;
    int v = 0;
    #pragma unroll
    for (int i = 0; i < 4; ++i) { int idx = base + i; if (idx < NSEG) v += cnt[idx]; }
    sc[t] = v; __syncthreads();
    for (int off = 1; off < 256; off <<= 1) {
        int x = (t >= off) ? sc[t - off] : 0;
        __syncthreads(); sc[t] += x; __syncthreads();
    }
    if (t == 255) sums[b] = sc[255];
}

__global__ __launch_bounds__(512) void scan_pass2(int* __restrict__ sums, int nb) {
    __shared__ int sc[512];
    int t = threadIdx.x;
    int v = (t < nb) ? sums[t] : 0;
    sc[t] = v; __syncthreads();
    for (int off = 1; off < 512; off <<= 1) {
        int x = (t >= off) ? sc[t - off] : 0;
        __syncthreads(); sc[t] += x; __syncthreads();
    }
    if (t < nb) sums[t] = sc[t] - v;     // exclusive
}

__global__ __launch_bounds__(256) void scan_pass3(const int* __restrict__ cnt,
                                                  const int* __restrict__ sums,
                                                  int* __restrict__ row_ptr) {
    __shared__ int sc[256];
    int b = blockIdx.x, t = threadIdx.x;
    int base = b * 1024 + t * 4;
    int e[4]; int v = 0;
    #pragma unroll
    for (int i = 0; i < 4; ++i) { int idx = base + i; e[i] = (idx < NSEG) ? cnt[idx] : 0; v += e[i]; }
    sc[t] = v; __syncthreads();
    for (int off = 1; off < 256; off <<= 1) {
        int x = (t >= off) ? sc[t - off] : 0;
        __syncthreads(); sc[t] += x; __syncthreads();
    }
    int run = sums[b] + (sc[t] - v);
    #pragma unroll
    for (int i = 0; i < 4; ++i) {
        int idx = base + i;
        if (idx < NSEG) row_ptr[idx] = run;
        run += e[i];
    }
    if (b == 0 && t == 0) row_ptr[NSEG] = N_EDGES;
}

// cnt doubles as the placement cursor (atomicSub); cnt is dead afterwards.
__global__ void place_edges(const int* __restrict__ src, const int* __restrict__ dst,
                            const int* __restrict__ et, const int* __restrict__ row_ptr,
                            int* __restrict__ cnt, int* __restrict__ sorted_src) {
    int e = blockIdx.x * 256 + threadIdx.x;
    if (e >= N_EDGES) return;
    int key = et[e] * N_NODES + dst[e];
    int old = atomicSub(&cnt[key], 1);
    sorted_src[row_ptr[key] + old - 1] = src[e];
}

// ---------------- weight pack: BT[col][k] bf16, col = r*O+o (r=8 -> root), zero-pad cols ----------------

__global__ void convert_weights(const float* __restrict__ W, const float* __restrict__ root,
                                ushort* __restrict__ BT, int K, int O, int NPAD) {
    int idx = blockIdx.x * 256 + threadIdx.x;
    if (idx >= NPAD * K) return;
    int col = idx / K, i = idx % K;
    float v = 0.0f;
    if (col < N_REL * O) {
        int r = col / O, o = col % O;
        v = W[((size_t)r * K + i) * O + o];
    } else if (col < (N_REL + 1) * O) {
        v = root[(size_t)i * O + (col - N_REL * O)];
    }
    BT[idx] = f2bf(v);
}

__global__ void f32_to_bf16(const float* __restrict__ in, ushort* __restrict__ out, int n4) {
    int i = blockIdx.x * 256 + threadIdx.x;
    if (i >= n4) return;
    float4 v = ((const float4*)in)[i];
    ushort4 s; s.x = f2bf(v.x); s.y = f2bf(v.y); s.z = f2bf(v.z); s.w = f2bf(v.w);
    ((ushort4*)out)[i] = s;
}

// ---------------- bf16 MFMA GEMM (round-7 kernel + XCD-pinned swizzle) ----------------
// 1-D grid, swizzled so ALL CTS col-blocks of a 128-row stripe land on ONE XCD
// (dispatch round-robins id%8 across XCDs, m09): the stripe's A-tile (64 KB) is
// fetched into that XCD's L2 once and served to the other col-blocks locally —
// attacks round-7's 112 MB residual FETCH (A re-read ~4.5x across 8 L2s).
// Epilogue: two-pass 32-row LDS transpose -> full-line 128 B coalesced stores.
template<int K, int CTS>
__global__ __launch_bounds__(256)
void gemm_mfma(const ushort* __restrict__ A, const ushort* __restrict__ BT,
               ushort* __restrict__ Y, int NW) {
    // ---- swizzle: f -> (stripe y, col-tile ct) pinned to XCD f&7 ----
    const int f = blockIdx.x;
    const int g = f & 7, m = f >> 3;
    const int y = g + 8 * (m / CTS);
    const int ct = m % CTS;
    if (y >= NSTRIPE) return;               // uniform early-exit (before any barrier)
    const int row0 = y * 128;
    const int col0 = ct * 128;

    __shared__ ushort SMEM[9216];           // 18432 B: k-loop As|Bs (16 KB) / epilogue Ts
    ushort* As = SMEM;                      // 128*32 = 4096 ushorts
    ushort* Bs = SMEM + 4096;
    const int t = threadIdx.x;
    const int lane = t & 63;
    const int w = t >> 6;
    const int l16 = lane & 15, q = lane >> 4;
    const int wm = (w & 1) * 64, wn = (w >> 1) * 64;

    // staging: chunk c (0..511) = 16B; row = c>>2, kcol = (c&3)*8. Wave w handles
    // chunks [w*64, w*64+64) and [(w+4)*64, ...): LDS dst = wave-uniform base + lane*16.
    const int c0i = w * 64 + lane;
    const int c1i = c0i + 256;
    const size_t ga0 = (size_t)(c0i >> 2) * K + (size_t)(c0i & 3) * 8;
    const size_t ga1 = (size_t)(c1i >> 2) * K + (size_t)(c1i & 3) * 8;
    const ushort* Ab = A + (size_t)row0 * K;
    const ushort* Bb = BT + (size_t)col0 * K;
    ushort* lA0 = &As[w * 512];
    ushort* lA1 = &As[(w + 4) * 512];
    ushort* lB0 = &Bs[w * 512];
    ushort* lB1 = &Bs[(w + 4) * 512];

    f32x4 acc[4][4] = {};

    #pragma unroll
    for (int k0 = 0; k0 < K; k0 += 32) {
        __syncthreads();                    // previous iter's LDS reads done
        async16(Ab + k0 + ga0, lA0);
        async16(Ab + k0 + ga1, lA1);
        async16(Bb + k0 + ga0, lB0);
        async16(Bb + k0 + ga1, lB1);
        __syncthreads();                    // drains global_load_lds (vmcnt 0)
        bf16x8 a[4], b[4];
        #pragma unroll
        for (int i = 0; i < 4; ++i) {
            a[i] = *(const bf16x8*)&As[(wm + i * 16 + l16) * 32 + q * 8];
            b[i] = *(const bf16x8*)&Bs[(wn + i * 16 + l16) * 32 + q * 8];
        }
        #pragma unroll
        for (int i = 0; i < 4; ++i)
            #pragma unroll
            for (int j = 0; j < 4; ++j)
                acc[i][j] = __builtin_amdgcn_mfma_f32_16x16x32_bf16(a[i], b[j], acc[i][j], 0, 0, 0);
    }

    // ---- epilogue: two-pass transpose via wave-private LDS (32 rows x stride 72),
    // then full-line stores: 8 lanes cover 128 B of one row per instruction.
    __syncthreads();                        // k-loop LDS reads done; reuse SMEM as Ts
    ushort* Ts = &SMEM[w * 32 * 72];
    const int rr = lane >> 3;               // 0..7 row within 8-row group
    const int cc = (lane & 7) * 8;          // 16B chunk within row
    #pragma unroll
    for (int half = 0; half < 2; ++half) {
        // scatter: D mapping col=l16, row=q*4+reg (verified gfx950 layout)
        #pragma unroll
        for (int i = 0; i < 2; ++i)
            #pragma unroll
            for (int j = 0; j < 4; ++j)
                #pragma unroll
                for (int r = 0; r < 4; ++r)
                    Ts[(i * 16 + q * 4 + r) * 72 + j * 16 + l16] = f2bf(acc[half * 2 + i][j][r]);
        // gather+store (wave-private region; compiler orders LDS ops via lgkmcnt)
        #pragma unroll
        for (int p = 0; p < 4; ++p) {
            int row = p * 8 + rr;           // 0..31 local
            uint4 v = *(const uint4*)&Ts[row * 72 + cc];
            *(uint4*)(Y + (size_t)(row0 + wm + half * 32 + row) * NW + col0 + wn + cc) = v;
        }
    }
}

// ---------------- fused gather: out[d] = act( root + bias + sum_r mean_r ) ----------------
// Thread owns (dst node, 8-col chunk); segment bounds preloaded for MLP; no atomics.
template<int O>
__global__ __launch_bounds__(256)
void gather_kernel(const ushort* __restrict__ Y, int NW,
                   const int* __restrict__ row_ptr, const int* __restrict__ sorted_src,
                   const float* __restrict__ bias,
                   float* __restrict__ out_f32, ushort* __restrict__ out_bf16, int relu) {
    constexpr int TPN = O / 8;
    int d = blockIdx.x * (256 / TPN) + threadIdx.x / TPN;
    if (d >= N_NODES) return;
    int c0 = (threadIdx.x % TPN) * 8;
    int s0[N_REL], s1[N_REL];
    #pragma unroll
    for (int r = 0; r < N_REL; ++r) {
        s0[r] = row_ptr[r * N_NODES + d];
        s1[r] = row_ptr[r * N_NODES + d + 1];
    }
    float sum[8] = {};
    add8(sum, *(const uint4*)(Y + (size_t)d * NW + N_REL * O + c0));   // root slice
    #pragma unroll
    for (int k = 0; k < 8; ++k) sum[k] += bias[c0 + k];
    for (int r = 0; r < N_REL; ++r) {
        if (s1[r] <= s0[r]) continue;
        float ps[8] = {};
        const ushort* Yc = Y + r * O + c0;
        for (int e = s0[r]; e < s1[r]; ++e)
            add8(ps, *(const uint4*)(Yc + (size_t)sorted_src[e] * NW));
        float inv = 1.0f / (float)(s1[r] - s0[r]);
        #pragma unroll
        for (int k = 0; k < 8; ++k) sum[k] += ps[k] * inv;
    }
    if (relu) {
        #pragma unroll
        for (int k = 0; k < 8; ++k) sum[k] = fmaxf(sum[k], 0.0f);
    }
    if (out_bf16) {
        ushort o[8];
        #pragma unroll
        for (int k = 0; k < 8; ++k) o[k] = f2bf(sum[k]);
        *(uint4*)(out_bf16 + (size_t)d * O + c0) = *(const uint4*)o;
    } else {
        float* p = out_f32 + (size_t)d * O + c0;
        *(float4*)p = make_float4(sum[0], sum[1], sum[2], sum[3]);
        *(float4*)(p + 4) = make_float4(sum[4], sum[5], sum[6], sum[7]);
    }
}

// ---------------- host side ----------------

extern "C" void kernel_launch(void* const* d_in, const int* in_sizes, int n_in,
                              void* d_out, int out_size, void* d_ws, size_t ws_size,
                              hipStream_t stream) {
    const float* x  = (const float*)d_in[0];
    const int*   ei = (const int*)d_in[1];
    const int*   et = (const int*)d_in[2];
    const float* W[4]  = {(const float*)d_in[3], (const float*)d_in[6], (const float*)d_in[9],  (const float*)d_in[12]};
    const float* RT[4] = {(const float*)d_in[4], (const float*)d_in[7], (const float*)d_in[10], (const float*)d_in[13]};
    const float* BI[4] = {(const float*)d_in[5], (const float*)d_in[8], (const float*)d_in[11], (const float*)d_in[14]};
    const int KS[4] = {128, 256, 256, 256};
    const int NP[4] = {2304, 2304, 2304, 640};   // packed+padded BT rows (= Y width)
    const int* src = ei;
    const int* dst = ei + N_EDGES;

    // ---- workspace carve-up (same footprint as proven round-3 plan A) ----
    char* ws = (char*)d_ws;
    size_t off = 0;
    auto take = [&](size_t bytes) -> char* {
        char* p = ws + off;
        off = (off + bytes + 255) & ~(size_t)255;
        return p;
    };
    int* cnt        = (int*)take((size_t)NSEG * 4);
    int* row_ptr    = (int*)take((size_t)(NSEG + 1) * 4);
    int* sums       = (int*)take(512 * 4);
    int* sorted_src = (int*)take((size_t)N_EDGES * 4);
    ushort* BTp[4];
    for (int l = 0; l < 4; ++l) BTp[l] = (ushort*)take((size_t)NP[l] * KS[l] * 2);
    ushort* hb = (ushort*)take((size_t)N_PAD * 256 * 2);
    ushort* Yb = (ushort*)take((size_t)N_PAD * 2304 * 2);

    // ---- edge preprocessing (once per call) ----
    hipMemsetAsync(cnt, 0, (size_t)NSEG * 4, stream);
    count_edges<<<(N_EDGES + 255) / 256, 256, 0, stream>>>(dst, et, cnt);
    scan_pass1<<<SCAN_NB, 256, 0, stream>>>(cnt, sums);
    scan_pass2<<<1, 512, 0, stream>>>(sums, SCAN_NB);
    scan_pass3<<<SCAN_NB, 256, 0, stream>>>(cnt, sums, row_ptr);
    place_edges<<<(N_EDGES + 255) / 256, 256, 0, stream>>>(src, dst, et, row_ptr, cnt, sorted_src);

    // ---- weight pack ----
    for (int l = 0; l < 4; ++l) {
        int n = NP[l] * KS[l];
        convert_weights<<<(n + 255) / 256, 256, 0, stream>>>(W[l], RT[l], BTp[l], KS[l], 
                                                             l == 3 ? 64 : 256, NP[l]);
    }

    // ---- input to bf16 ----
    f32_to_bf16<<<(N_NODES * 128 / 4 + 255) / 256, 256, 0, stream>>>(x, hb, N_NODES * 128 / 4);

    // ---- 4 layers: XCD-swizzled GEMM + fused gather ----
    const int G18 = 8 * SPX * 18;   // 7056
    const int G5  = 8 * SPX * 5;    // 1960
    gemm_mfma<128, 18><<<G18, 256, 0, stream>>>(hb, BTp[0], Yb, 2304);
    gather_kernel<256><<<dim3((N_NODES + 7) / 8), 256, 0, stream>>>(
        Yb, 2304, row_ptr, sorted_src, BI[0], nullptr, hb, 1);

    gemm_mfma<256, 18><<<G18, 256, 0, stream>>>(hb, BTp[1], Yb, 2304);
    gather_kernel<256><<<dim3((N_NODES + 7) / 8), 256, 0, stream>>>(
        Yb, 2304, row_ptr, sorted_src, BI[1], nullptr, hb, 1);

    gemm_mfma<256, 18><<<G18, 256, 0, stream>>>(hb, BTp[2], Yb, 2304);
    gather_kernel<256><<<dim3((N_NODES + 7) / 8), 256, 0, stream>>>(
        Yb, 2304, row_ptr, sorted_src, BI[2], nullptr, hb, 1);

    gemm_mfma<256, 5><<<G5, 256, 0, stream>>>(hb, BTp[3], Yb, 640);
    gather_kernel<64><<<dim3((N_NODES + 31) / 32), 256, 0, stream>>>(
        Yb, 640, row_ptr, sorted_src, BI[3], (float*)d_out, nullptr, 0);
}